// Round 1
// 4410.614 us; speedup vs baseline: 1.0773x; 1.0773x over previous
//
#include <hip/hip_runtime.h>
#include <hip/hip_bf16.h>

// B=64, S=512, T=64, E=H=512, V=128, G=4H=2048, Kgates=512(ctx)+512(h)+128(tgt)=1152
// R2: latency/sync-bound fix. 512 thr/block (8 waves/CU), 2 grid barriers/step
// (cell fused into attention blocks, c in registers), transposed layouts for
// conflict-free coalesced staging, async global->LDS pre-stage of weight tile.

#define DI __device__ __forceinline__
typedef __hip_bfloat16 bf16;
typedef __hip_bfloat162 bf162;

DI float2 bf2f2(unsigned int u) {
  bf162 b = *reinterpret_cast<const bf162*>(&u);
  return __bfloat1622float2(b);
}
DI float sigm(float x) { return 1.f / (1.f + expf(-x)); }

// ---------------------------------------------------------------------------
// Generic 64x64-tile fp32 GEMM (precompute only, unchanged from R1)
// ---------------------------------------------------------------------------
template<bool BT, bool OBF, bool CT>
__launch_bounds__(256)
__global__ void gemm64(const float* __restrict__ A, const float* __restrict__ Bm,
                       void* __restrict__ Cp, const float* __restrict__ bias,
                       int M, int N, int K, int lda, int ldb, int ldc) {
  __shared__ __align__(16) float As[16][68];
  __shared__ __align__(16) float Bs[16][68];
  const int tid = threadIdx.x;
  const int n0 = blockIdx.x * 64;
  const int m0 = blockIdx.y * 64;
  const int tx = tid & 15, ty = tid >> 4;
  const int arow = tid >> 2;
  const int acol = (tid & 3) * 4;
  float acc[4][4] = {};
  for (int k0 = 0; k0 < K; k0 += 16) {
    float4 a4 = *(const float4*)&A[(size_t)(m0 + arow) * lda + k0 + acol];
    As[acol + 0][arow] = a4.x; As[acol + 1][arow] = a4.y;
    As[acol + 2][arow] = a4.z; As[acol + 3][arow] = a4.w;
    if (BT) {
      float4 b4 = *(const float4*)&Bm[(size_t)(n0 + arow) * ldb + k0 + acol];
      Bs[acol + 0][arow] = b4.x; Bs[acol + 1][arow] = b4.y;
      Bs[acol + 2][arow] = b4.z; Bs[acol + 3][arow] = b4.w;
    } else {
      const int brow = tid >> 4;
      const int bcol = (tid & 15) * 4;
      float4 b4 = *(const float4*)&Bm[(size_t)(k0 + brow) * ldb + n0 + bcol];
      *(float4*)&Bs[brow][bcol] = b4;
    }
    __syncthreads();
#pragma unroll
    for (int kk = 0; kk < 16; kk++) {
      float4 av = *(const float4*)&As[kk][ty * 4];
      float4 bv = *(const float4*)&Bs[kk][tx * 4];
      float a_[4] = {av.x, av.y, av.z, av.w};
      float b_[4] = {bv.x, bv.y, bv.z, bv.w};
#pragma unroll
      for (int i = 0; i < 4; i++)
#pragma unroll
        for (int j = 0; j < 4; j++) acc[i][j] += a_[i] * b_[j];
    }
    __syncthreads();
  }
#pragma unroll
  for (int i = 0; i < 4; i++) {
    const int m = m0 + ty * 4 + i;
#pragma unroll
    for (int j = 0; j < 4; j++) {
      const int n = n0 + tx * 4 + j;
      float v = acc[i][j] + (bias ? bias[n] : 0.f);
      if (OBF) {
        if (CT) {
          int bb = m >> 9, sE = m & 511;
          ((bf16*)Cp)[((size_t)bb << 18) + (size_t)n * 512 + sE] = __float2bfloat16(v);
        } else {
          ((bf16*)Cp)[(size_t)m * ldc + n] = __float2bfloat16(v);
        }
      } else {
        ((float*)Cp)[(size_t)m * ldc + n] = v;
      }
    }
  }
}

// ---------------------------------------------------------------------------
// Small precompute kernels
// ---------------------------------------------------------------------------
__launch_bounds__(256)
__global__ void transpose512(const float* __restrict__ src, float* __restrict__ dst) {
  int idx = blockIdx.x * 256 + threadIdx.x;
  int r = idx >> 9, c = idx & 511;
  dst[(size_t)c * 512 + r] = src[idx];
}

__launch_bounds__(256)
__global__ void colvec_kernel(const float* __restrict__ bvec, const float* __restrict__ W,
                              float* __restrict__ outv) {
  int e = blockIdx.x * 256 + threadIdx.x;
  float acc = 0.f;
  for (int f = 0; f < 512; f++) acc += bvec[f] * W[(size_t)f * 512 + e];
  outv[e] = acc;
}

__launch_bounds__(256)
__global__ void dot_kernel(const float* __restrict__ a, const float* __restrict__ b,
                           float* __restrict__ outp) {
  __shared__ float red[256];
  int tid = threadIdx.x;
  red[tid] = a[tid] * b[tid] + a[tid + 256] * b[tid + 256];
  __syncthreads();
  for (int st = 128; st > 0; st >>= 1) {
    if (tid < st) red[tid] += red[tid + st];
    __syncthreads();
  }
  if (tid == 0) *outp = red[0];
}

__launch_bounds__(256)
__global__ void svec_kernel(const float* __restrict__ mem, const float* __restrict__ wb,
                            const float* __restrict__ dotc, float* __restrict__ svec) {
  __shared__ __align__(16) float ws_[512];
  int tid = threadIdx.x;
  *(float2*)&ws_[tid * 2] = *(const float2*)&wb[tid * 2];
  __syncthreads();
  int bs = blockIdx.x * 256 + tid;
  const float4* mr = (const float4*)&mem[(size_t)bs * 512];
  const float4* w4 = (const float4*)ws_;
  float acc = *dotc;
#pragma unroll 4
  for (int j = 0; j < 128; j++) {
    float4 m = mr[j], w = w4[j];
    acc += m.x * w.x + m.y * w.y + m.z * w.z + m.w * w.w;
  }
  svec[bs] = acc;
}

__launch_bounds__(256)
__global__ void biasg_kernel(const float* __restrict__ W_ih, const float* __restrict__ b_ih,
                             const float* __restrict__ b_hh, const float* __restrict__ bo,
                             float* __restrict__ biasg) {
  int j = blockIdx.x * 256 + threadIdx.x;
  float acc = b_ih[j] + b_hh[j];
  const float4* wr = (const float4*)&W_ih[(size_t)j * 640];
  const float4* br = (const float4*)bo;
#pragma unroll 4
  for (int f4 = 0; f4 < 128; f4++) {
    float4 w = wr[f4], bb = br[f4];
    acc += w.x * bb.x + w.y * bb.y + w.z * bb.z + w.w * bb.w;
  }
  biasg[j] = acc;
}

__launch_bounds__(256)
__global__ void wcomb_copy(const float* __restrict__ W_hh, const float* __restrict__ W_ih,
                           float* __restrict__ Wcomb) {
  int idx = blockIdx.x * 256 + threadIdx.x;
  int j = idx / 640, cc = idx % 640;
  float v = (cc < 512) ? W_hh[(size_t)j * 512 + cc] : W_ih[(size_t)j * 640 + cc];
  Wcomb[(size_t)j * 1152 + 512 + cc] = v;
}

// WcombT[k][n] = Wcomb[n][k]  (1152 x 2048)
__launch_bounds__(256)
__global__ void transposeWc(const float* __restrict__ src, float* __restrict__ dst) {
  __shared__ float tile[32][33];
  const int n0 = blockIdx.x * 32, k0 = blockIdx.y * 32;
  const int x = threadIdx.x & 31, y0 = threadIdx.x >> 5;
  for (int y = y0; y < 32; y += 8)
    tile[y][x] = src[(size_t)(n0 + y) * 1152 + k0 + x];
  __syncthreads();
  for (int y = y0; y < 32; y += 8)
    dst[(size_t)(k0 + y) * 2048 + n0 + x] = tile[x][y];
}

// tgtT[t][v][b] = tgt[b][t][v]
__launch_bounds__(256)
__global__ void build_tgtT(const float* __restrict__ tgt, float* __restrict__ tgtT) {
  int idx = blockIdx.x * 256 + threadIdx.x;   // < 524288
  int b = idx & 63;
  int rest = idx >> 6;
  int v = rest & 127, tt = rest >> 7;
  tgtT[idx] = tgt[((size_t)b * 64 + tt) * 128 + v];
}

// ---------------------------------------------------------------------------
// Persistent step-loop kernel: 256 blocks x 512 threads, 2 grid barriers/step.
// ---------------------------------------------------------------------------
DI void gbar(unsigned* flags, unsigned* go, int slot) {
  const unsigned tgt = (unsigned)slot + 1u;
  __syncthreads();
  if (threadIdx.x == 0) {
    __threadfence();   // release: L2 writeback (cross-XCD visibility)
    __hip_atomic_store(&flags[blockIdx.x], tgt, __ATOMIC_RELAXED, __HIP_MEMORY_SCOPE_AGENT);
  }
  if (blockIdx.x == 0) {
    if (threadIdx.x < 256)
      while (__hip_atomic_load(&flags[threadIdx.x], __ATOMIC_RELAXED, __HIP_MEMORY_SCOPE_AGENT) < tgt)
        __builtin_amdgcn_s_sleep(1);
    __syncthreads();
    if (threadIdx.x == 0) {
      __threadfence();
      __hip_atomic_store(go, tgt, __ATOMIC_RELAXED, __HIP_MEMORY_SCOPE_AGENT);
    }
  }
  if (threadIdx.x == 0) {
    while (__hip_atomic_load(go, __ATOMIC_RELAXED, __HIP_MEMORY_SCOPE_AGENT) < tgt)
      __builtin_amdgcn_s_sleep(1);
    __threadfence();   // acquire: invalidate caches
  }
  __syncthreads();
}

__launch_bounds__(512, 2)
__global__ void step_loop(const bf16* __restrict__ K2T, const bf16* __restrict__ Vv,
                          const float* __restrict__ svec, const float* __restrict__ WcombT,
                          const float* __restrict__ biasg, const float* __restrict__ tgtT,
                          const float* __restrict__ Wcls, const float* __restrict__ bcls,
                          float* __restrict__ hT, float* __restrict__ cpart,
                          float* __restrict__ mlval, unsigned* __restrict__ mlcnt,
                          unsigned* flags, unsigned* go,
                          float* __restrict__ gpart, float* __restrict__ out) {
  __shared__ __align__(16) float hs[512];
  __shared__ __align__(16) float abuf[4224];   // scores: 32x132; ctx: 8x512
  __shared__ __align__(16) float pbuf[128];
  __shared__ float red2[2];
  __shared__ float mlc[8];
  __shared__ __align__(16) float As[144][64];  // gates A tile (row = k, col = batch)
  __shared__ __align__(16) float Bs[144][64];  // gates W tile (row = k, col = n)

  const int blk = blockIdx.x, tid = threadIdx.x;
  const int b = blk >> 2, jj = blk & 3, s0 = jj * 128;
  const int ks = blk >> 5, n0q = (blk & 31) * 64, k0 = ks * 144;
  const float SCALE = 0.04419417382415922f;  // 1/sqrt(512)
  float creg = 0.f;                          // LSTM c state lives in a register
  int slot = 0;

  for (int t = 0; t <= 64; t++) {
    // ---- LSTM cell: reduce gpart(t-1) -> h_t (all 4 siblings, redundant) ----
    if (t > 0) {
      const int d = tid;
      float g0 = biasg[d], g1 = biasg[512 + d], g2 = biasg[1024 + d], g3 = biasg[1536 + d];
      const float* gp = gpart + (size_t)b * 2048 + d;
#pragma unroll
      for (int ksq = 0; ksq < 8; ksq++) {
        const float* gq = gp + (size_t)ksq * 131072;
        g0 += gq[0]; g1 += gq[512]; g2 += gq[1024]; g3 += gq[1536];
      }
      const float cn = sigm(g1) * creg + sigm(g0) * tanhf(g2);
      const float hn = sigm(g3) * tanhf(cn);
      creg = cn;
      hs[d] = hn;
      if ((d >> 7) == jj) hT[(size_t)d * 64 + b] = hn;   // quarter-owner writes hT[k][b]
    } else {
      hs[tid] = 0.f;
    }
    __syncthreads();

    // ---- classifier: out[:, t-1, :] = h_t @ Wcls^T + bcls ----
    if (t > 0) {
      const int vl = tid >> 4, part = tid & 15;
      const int v = jj * 32 + vl;
      const float4* wr = (const float4*)&Wcls[(size_t)v * 512 + part * 32];
      const float4* hr = (const float4*)&hs[part * 32];
      float a = 0.f;
#pragma unroll
      for (int q = 0; q < 8; q++) {
        float4 w = wr[q], hh = hr[q];
        a += w.x * hh.x + w.y * hh.y + w.z * hh.z + w.w * hh.w;
      }
      a += __shfl_xor(a, 1); a += __shfl_xor(a, 2);
      a += __shfl_xor(a, 4); a += __shfl_xor(a, 8);
      if (part == 0) out[((size_t)b * 64 + (t - 1)) * 128 + v] = a + bcls[v];
    }
    if (t == 64) return;

    // ---- async pre-stage of Bs (WcombT tile) via global->LDS DMA ----
    // Independent of phase-A results; streams under the attention compute.
    {
      const int wv = tid >> 6, l = tid & 63;
      const int r4 = l >> 4, c4 = (l & 15) * 4;
      for (int i = wv; i < 36; i += 8) {
        const float* gsrc = &WcombT[(size_t)(k0 + 4 * i + r4) * 2048 + n0q + c4];
        __builtin_amdgcn_global_load_lds(
            (const __attribute__((address_space(1))) void*)gsrc,
            (__attribute__((address_space(3))) void*)&Bs[4 * i][0], 16, 0, 0);
      }
    }

    // ---- attention scores: p[s] = h . K2T[b][:][s0+s] ----
    float pv = 0.f;
    {
      const int eo = tid >> 4, so = tid & 15;
      float a8[8] = {};
      const uint4* kp = (const uint4*)&K2T[((size_t)b << 18) + (size_t)(eo * 16) * 512 + s0 + 8 * so];
#pragma unroll 8
      for (int i = 0; i < 16; i++) {
        uint4 q = kp[(size_t)i * 64];
        float he = hs[eo * 16 + i];
        float2 p0 = bf2f2(q.x), p1 = bf2f2(q.y), p2 = bf2f2(q.z), p3 = bf2f2(q.w);
        a8[0] += he * p0.x; a8[1] += he * p0.y; a8[2] += he * p1.x; a8[3] += he * p1.y;
        a8[4] += he * p2.x; a8[5] += he * p2.y; a8[6] += he * p3.x; a8[7] += he * p3.y;
      }
      // stride-132 rows -> ideal 8 words/bank, conflict-free float4 stores
      *(float4*)&abuf[eo * 132 + so * 8]     = make_float4(a8[0], a8[1], a8[2], a8[3]);
      *(float4*)&abuf[eo * 132 + so * 8 + 4] = make_float4(a8[4], a8[5], a8[6], a8[7]);
    }
    __syncthreads();
    if (tid < 128) {
      float sv = 0.f;
#pragma unroll
      for (int eo = 0; eo < 32; eo++) sv += abuf[eo * 132 + tid];
      pv = (sv + svec[(size_t)b * 512 + s0 + tid]) * SCALE;
      pbuf[tid] = pv;
    }
    __syncthreads();
    if (tid < 64) {
      float v = fmaxf(pbuf[tid], pbuf[tid + 64]);
#pragma unroll
      for (int off = 32; off; off >>= 1) v = fmaxf(v, __shfl_down(v, off));
      if (tid == 0) red2[0] = v;
    }
    __syncthreads();
    const float mloc = red2[0];
    if (tid < 128) pbuf[tid] = __expf(pv - mloc);
    __syncthreads();
    if (tid < 64) {
      float v = pbuf[tid] + pbuf[tid + 64];
#pragma unroll
      for (int off = 32; off; off >>= 1) v += __shfl_down(v, off);
      if (tid == 0) red2[1] = v;
    }
    __syncthreads();
    if (tid == 0) {
      const float lloc = red2[1];
      __hip_atomic_store(&mlval[(b * 4 + jj) * 2 + 0], mloc, __ATOMIC_RELAXED, __HIP_MEMORY_SCOPE_AGENT);
      __hip_atomic_store(&mlval[(b * 4 + jj) * 2 + 1], lloc, __ATOMIC_RELAXED, __HIP_MEMORY_SCOPE_AGENT);
      __hip_atomic_fetch_add(&mlcnt[b], 1u, __ATOMIC_RELEASE, __HIP_MEMORY_SCOPE_AGENT);
    }
    // ---- ctx partial: wave w covers s = 8i+w; lane l owns e in [8l, 8l+8) ----
    {
      const int w = tid >> 6, l = tid & 63;
      float c8[8] = {};
      const uint4* vp = (const uint4*)&Vv[((size_t)b << 18) + (size_t)s0 * 512 + 8 * l];
#pragma unroll 8
      for (int i = 0; i < 16; i++) {
        const int s = i * 8 + w;
        const float ps = pbuf[s];
        uint4 q = vp[(size_t)s * 64];
        float2 p0 = bf2f2(q.x), p1 = bf2f2(q.y), p2 = bf2f2(q.z), p3 = bf2f2(q.w);
        c8[0] += ps * p0.x; c8[1] += ps * p0.y; c8[2] += ps * p1.x; c8[3] += ps * p1.y;
        c8[4] += ps * p2.x; c8[5] += ps * p2.y; c8[6] += ps * p3.x; c8[7] += ps * p3.y;
      }
      // parity-swizzled float4 pair: each store instruction covers all 8 bank quads
      const int k2 = (l >> 2) & 1, sw = k2 << 2;
      float4 lo = make_float4(c8[0], c8[1], c8[2], c8[3]);
      float4 hi = make_float4(c8[4], c8[5], c8[6], c8[7]);
      float4 first  = k2 ? hi : lo;
      float4 second = k2 ? lo : hi;
      const int base = w * 512 + 8 * l;
      *(float4*)&abuf[base + sw]     = first;
      *(float4*)&abuf[base + 4 - sw] = second;
    }
    // wait for all 4 sibling (m,l) posts of this b
    if (tid == 0)
      while (__hip_atomic_load(&mlcnt[b], __ATOMIC_RELAXED, __HIP_MEMORY_SCOPE_AGENT) < 4u * (t + 1))
        __builtin_amdgcn_s_sleep(1);
    __syncthreads();
    if (tid < 8)
      mlc[tid] = __hip_atomic_load(&mlval[b * 8 + tid], __ATOMIC_RELAXED, __HIP_MEMORY_SCOPE_AGENT);
    __syncthreads();
    {
      const float M = fmaxf(fmaxf(mlc[0], mlc[2]), fmaxf(mlc[4], mlc[6]));
      const float L = __expf(mlc[0] - M) * mlc[1] + __expf(mlc[2] - M) * mlc[3]
                    + __expf(mlc[4] - M) * mlc[5] + __expf(mlc[6] - M) * mlc[7];
      const float msc = __expf(mlc[2 * jj] - M) / L;
      float cx = 0.f;
#pragma unroll
      for (int w = 0; w < 8; w++) cx += abuf[w * 512 + tid];
      cpart[(size_t)jj * 32768 + (size_t)tid * 64 + b] = cx * msc;  // [jj][e][b]
    }
    gbar(flags, go, slot++);

    // ======= gates GEMM: 64x64x144 tile, intra-block split-K (2 x 72) =======
    {
      // stage As rows (k-dependent gather; transposed sources -> coalesced f4)
#pragma unroll
      for (int q = 0; q < 5; q++) {
        const int idx = tid + q * 512;
        if (idx < 2304) {
          const int kk = idx >> 4, m4 = (idx & 15) * 4;
          const int k = k0 + kk;
          float4 xv;
          if (k < 512) {
            const float* cp = cpart + (size_t)k * 64 + m4;
            const float4 x0 = *(const float4*)(cp);
            const float4 x1 = *(const float4*)(cp + 32768);
            const float4 x2 = *(const float4*)(cp + 65536);
            const float4 x3 = *(const float4*)(cp + 98304);
            xv = make_float4(x0.x + x1.x + x2.x + x3.x, x0.y + x1.y + x2.y + x3.y,
                             x0.z + x1.z + x2.z + x3.z, x0.w + x1.w + x2.w + x3.w);
          } else if (k < 1024) {
            xv = *(const float4*)&hT[(size_t)(k - 512) * 64 + m4];
          } else {
            xv = *(const float4*)&tgtT[((size_t)t * 128 + (k - 1024)) * 64 + m4];
          }
          *(float4*)&As[kk][m4] = xv;
        }
      }
      __syncthreads();
      const int hi2 = tid >> 8, t8 = tid & 255;
      const int tx = t8 & 15, ty = t8 >> 4;
      const int kb = hi2 * 72;
      float acc[4][4] = {};
#pragma unroll 4
      for (int kk = 0; kk < 72; kk++) {
        const float4 av = *(const float4*)&As[kb + kk][ty * 4];
        const float4 bv = *(const float4*)&Bs[kb + kk][tx * 4];
        const float a_[4] = {av.x, av.y, av.z, av.w};
        const float b_[4] = {bv.x, bv.y, bv.z, bv.w};
#pragma unroll
        for (int i = 0; i < 4; i++)
#pragma unroll
          for (int j = 0; j < 4; j++) acc[i][j] += a_[i] * b_[j];
      }
      __syncthreads();
      float* scratch = &As[0][0];
      if (hi2) {
#pragma unroll
        for (int i = 0; i < 4; i++)
#pragma unroll
          for (int j = 0; j < 4; j++) scratch[(i * 4 + j) * 256 + t8] = acc[i][j];
      }
      __syncthreads();
      if (!hi2) {
#pragma unroll
        for (int i = 0; i < 4; i++) {
          float4 vv;
          vv.x = acc[i][0] + scratch[(i * 4 + 0) * 256 + t8];
          vv.y = acc[i][1] + scratch[(i * 4 + 1) * 256 + t8];
          vv.z = acc[i][2] + scratch[(i * 4 + 2) * 256 + t8];
          vv.w = acc[i][3] + scratch[(i * 4 + 3) * 256 + t8];
          *(float4*)&gpart[(size_t)ks * 131072 + (size_t)(ty * 4 + i) * 2048 + n0q + tx * 4] = vv;
        }
      }
    }
    gbar(flags, go, slot++);
  }
}

// ---------------------------------------------------------------------------
extern "C" void kernel_launch(void* const* d_in, const int* in_sizes, int n_in,
                              void* d_out, int out_size, void* d_ws, size_t ws_size,
                              hipStream_t stream) {
  const float* memory = (const float*)d_in[0];
  const float* tgt    = (const float*)d_in[1];
  const float* Wq     = (const float*)d_in[2];
  const float* bq     = (const float*)d_in[3];
  const float* Wk     = (const float*)d_in[4];
  const float* bk     = (const float*)d_in[5];
  const float* Wv     = (const float*)d_in[6];
  const float* bv     = (const float*)d_in[7];
  const float* Wo     = (const float*)d_in[8];
  const float* bo     = (const float*)d_in[9];
  const float* W_ih   = (const float*)d_in[10];
  const float* b_ih   = (const float*)d_in[11];
  const float* W_hh   = (const float*)d_in[12];
  const float* b_hh   = (const float*)d_in[13];
  const float* Wcls   = (const float*)d_in[14];
  const float* bcls   = (const float*)d_in[15];
  float* out = (float*)d_out;

  float* ws = (float*)d_ws;
  size_t off = 0;
  auto alloc = [&](size_t n) { size_t r = off; off += (n + 15) & ~(size_t)15; return r; };
  const size_t K2_off     = alloc(8388608);   // bf16 x 16777216: K2T [b][e][s]
  const size_t V_off      = alloc(8388608);   // bf16 x 16777216: V  [b][s][e]
  const size_t Wcomb_off  = alloc(2359296);   // 2048 x 1152 (row-major, staging)
  const size_t WcombT_off = alloc(2359296);   // 1152 x 2048 (k-major for GEMM)
  const size_t Wkq_off    = alloc(262144);
  const size_t WkT_off    = alloc(262144);
  const size_t svec_off   = alloc(32768);
  const size_t sb_off     = alloc(512);
  const size_t wb_off     = alloc(512);
  const size_t dotc_off   = alloc(16);
  const size_t biasg_off  = alloc(2048);
  const size_t tgtT_off   = alloc(524288);    // [t][v][b]
  const size_t hT_off     = alloc(32768);     // [k][b]
  const size_t sync_off   = alloc(512);       // flags[256], go@272, mlcnt@384
  const size_t cpart_off  = alloc(131072);    // [jj][e][b]
  const size_t mlval_off  = alloc(512);
  const size_t gpart_off  = alloc(1048576);   // 8 x 64 x 2048

  bf16* K2T = (bf16*)(ws + K2_off);
  bf16* Vv  = (bf16*)(ws + V_off);
  unsigned* flags = (unsigned*)(ws + sync_off);
  unsigned* go    = flags + 272;
  unsigned* mlcnt = flags + 384;

  // zero hT and sync area in one shot (adjacent allocs)
  hipMemsetAsync(ws + hT_off, 0, (32768 + 512) * sizeof(float), stream);

  // ---- precompute (step-invariant) ----
  transpose512<<<1024, 256, 0, stream>>>(Wk, ws + WkT_off);
  colvec_kernel<<<2, 256, 0, stream>>>(bk, Wq, ws + sb_off);
  colvec_kernel<<<2, 256, 0, stream>>>(bq, Wk, ws + wb_off);
  dot_kernel<<<1, 256, 0, stream>>>(bq, bk, ws + dotc_off);
  gemm64<false, false, false><<<dim3(8, 8), 256, 0, stream>>>(
      ws + WkT_off, Wq, ws + Wkq_off, nullptr, 512, 512, 512, 512, 512, 512);
  gemm64<false, true, true><<<dim3(8, 512), 256, 0, stream>>>(
      memory, ws + Wkq_off, K2T, ws + sb_off, 32768, 512, 512, 512, 512, 512);
  gemm64<true, true, false><<<dim3(8, 512), 256, 0, stream>>>(
      memory, Wv, Vv, bv, 32768, 512, 512, 512, 512, 512);
  gemm64<false, false, false><<<dim3(8, 32), 256, 0, stream>>>(
      W_ih, Wo, ws + Wcomb_off, nullptr, 2048, 512, 512, 640, 512, 1152);
  wcomb_copy<<<5120, 256, 0, stream>>>(W_hh, W_ih, ws + Wcomb_off);
  transposeWc<<<dim3(64, 36), 256, 0, stream>>>(ws + Wcomb_off, ws + WcombT_off);
  biasg_kernel<<<8, 256, 0, stream>>>(W_ih, b_ih, b_hh, bo, ws + biasg_off);
  svec_kernel<<<128, 256, 0, stream>>>(memory, ws + wb_off, ws + dotc_off, ws + svec_off);
  build_tgtT<<<2048, 256, 0, stream>>>(tgt, ws + tgtT_off);

  // ---- all 64 recurrent steps in one persistent kernel ----
  step_loop<<<256, 512, 0, stream>>>(K2T, Vv, ws + svec_off, ws + WcombT_off,
                                     ws + biasg_off, ws + tgtT_off, Wcls, bcls,
                                     ws + hT_off, ws + cpart_off,
                                     ws + mlval_off, mlcnt, flags, go,
                                     ws + gpart_off, out);
}